// Round 1
// 722.023 us; speedup vs baseline: 1.1033x; 1.1033x over previous
//
#include <hip/hip_runtime.h>

#define NVEH 8192
#define NT   512

typedef short bf16x8 __attribute__((ext_vector_type(8)));
typedef float f32x4  __attribute__((ext_vector_type(4)));

__device__ __forceinline__ float fsig(float x) {
    float e = __builtin_amdgcn_exp2f(-1.44269504f * x);
    return __builtin_amdgcn_rcpf(1.0f + e);
}
__device__ __forceinline__ float ftanh(float x) {
    float e = __builtin_amdgcn_exp2f(-2.88539008f * x);
    return 2.0f * __builtin_amdgcn_rcpf(1.0f + e) - 1.0f;
}
__device__ __forceinline__ unsigned short f2bf(float f) {
    union { float f; unsigned u; } vv; vv.f = f;
    unsigned r = vv.u + 0x7fff + ((vv.u >> 16) & 1);
    return (unsigned short)(r >> 16);
}

// LDS-only barrier: order ds ops across waves WITHOUT draining vmcnt
// (plain __syncthreads() would wait vmcnt(0) and kill the global prefetch).
__device__ __forceinline__ void lds_barrier() {
    asm volatile("s_waitcnt lgkmcnt(0)" ::: "memory");
    __builtin_amdgcn_s_barrier();
    asm volatile("" ::: "memory");
}

// Two waves per 16-vehicle group. Wave0: z-MFMA tt=0..2 + gates for 12 units
// + x-pack + input prefetch. Wave1: z-MFMA tt=3..4 + gates for 8 units +
// head MFMA + lc reduce + store. Handoff through a double-buffered LDS row
// [x0..11 | h0..19] (bf16, 80 B stride) -> B-frag gather is one ds_read_b128.
__global__ __launch_bounds__(128) void lstm_scan_kernel(
    const float* __restrict__ lead, const float* __restrict__ traj,
    const float* __restrict__ hidden,
    const float* __restrict__ W_k, const float* __restrict__ W_r,
    const float* __restrict__ b_l, const float* __restrict__ W_d,
    const float* __restrict__ b_d, const float* __restrict__ W_lc,
    const float* __restrict__ b_lc,
    float* __restrict__ out_lc, float* __restrict__ out_h, float* __restrict__ out_c)
{
    // row[buf][v]: 40 shorts (80 B): [0..11]=x, [12..31]=h, [32..39]=pad.
    // 80 B stride -> b128 gather is 16B-aligned, ~2-way banks (free).
    __shared__ alignas(16) unsigned short row[2][16][40];

    const int tid  = threadIdx.x;
    const int wid  = tid >> 6;       // wave id 0/1
    const int lane = tid & 63;
    const int q    = lane >> 4;
    const int v    = lane & 15;
    const int gv   = blockIdx.x * 16 + v;

    const int TTB = wid ? 3 : 0;     // wave0: tt 0,1,2  wave1: tt 3,4

    // ---- z-MFMA fragments: A = W^T permuted (col p = 4u+g), bias as C
    bf16x8 aW[3]; f32x4 cB[3];
    #pragma unroll
    for (int l = 0; l < 3; ++l) {
        if (l < 2 || wid == 0) {
            const int tt = TTB + l;
            #pragma unroll
            for (int j = 0; j < 8; ++j) {
                int k = q * 8 + j;
                int p = 16 * tt + v;
                int u = p >> 2, g = p & 3;
                int col = g * 20 + u;
                float w = (k < 12) ? W_k[k * 80 + col] : W_r[(k - 12) * 80 + col];
                aW[l][j] = (short)f2bf(w);
            }
            #pragma unroll
            for (int reg = 0; reg < 4; ++reg)
                cB[l][reg] = b_l[reg * 20 + 4 * tt + q];
        }
    }

    // ---- wave1-only: head MFMA consts + lc stage consts
    bf16x8 aH = {};
    f32x4 cD = {};
    float wlc[4][3] = {};
    float pb0[3] = {};
    if (wid == 1) {
        #pragma unroll
        for (int j = 0; j < 8; ++j) {
            int k = q * 8 + j;
            aH[j] = (v < 10 && k >= 12) ? (short)f2bf(W_d[(k - 12) * 10 + v]) : (short)0;
        }
        #pragma unroll
        for (int reg = 0; reg < 4; ++reg) {
            int m = 4 * q + reg;
            cD[reg] = (m < 10) ? b_d[m] : 0.0f;
            #pragma unroll
            for (int j = 0; j < 3; ++j)
                wlc[reg][j] = (m < 10) ? W_lc[m * 3 + j] : 0.0f;
        }
        #pragma unroll
        for (int j = 0; j < 3; ++j) pb0[j] = (q == 0) ? b_lc[j] : 0.0f;
    }

    // ---- state + initial h publish into buf 1
    float h32[3], cst[3];
    #pragma unroll
    for (int l = 0; l < 3; ++l) {
        if (l < 2 || wid == 0) {
            int u = 4 * (TTB + l) + q;
            h32[l] = hidden[(size_t)gv * 20 + u];
            cst[l] = hidden[(size_t)NVEH * 20 + (size_t)gv * 20 + u];
            row[1][v][12 + u] = f2bf(h32[l]);
        }
    }

    // ---- per-lane x coefficients (elements 4q..4q+3): x = raw*Ac + pos*Bc
    float Ac[4], Bc[4];
    #pragma unroll
    for (int i = 0; i < 4; ++i) {
        int e = 4 * q + i;
        if (e < 3)      { Ac[i] =  0.01f;  Bc[i] = -0.01f; }
        else if (e < 6) { Ac[i] = -0.01f;  Bc[i] =  0.01f; }
        else            { Ac[i] =  0.025f; Bc[i] =  0.0f;  }
    }

    const float* lf = lead + (size_t)gv * NT * 12;
    const float* ps = traj + (size_t)gv * NT;
    float* lcout    = out_lc + (size_t)gv * NT * 3;

    // ---- wave0: x(0) pack + depth-3 prefetch
    float4 rA = make_float4(0.f,0.f,0.f,0.f), rB = rA, rC = rA;
    float pA = 0.f, pB = 0.f, pC = 0.f;
    if (wid == 0) {
        float4 r0 = make_float4(0.f,0.f,0.f,0.f); float p0s = 0.f;
        if (q < 3) r0 = *(const float4*)(lf + q * 4);
        if (q < 2) p0s = ps[0];
        if (q < 3) {
            float xv[4] = { r0.x, r0.y, r0.z, r0.w };
            #pragma unroll
            for (int i = 0; i < 4; ++i) {
                float x = fmaf(xv[i], Ac[i], p0s * Bc[i]);
                xv[i] = (x == x) ? x : 1.0f;
            }
            unsigned pk0 = (unsigned)f2bf(xv[0]) | ((unsigned)f2bf(xv[1]) << 16);
            unsigned pk1 = (unsigned)f2bf(xv[2]) | ((unsigned)f2bf(xv[3]) << 16);
            *(uint2*)&row[1][v][4 * q] = make_uint2(pk0, pk1);
        }
        if (q < 3) {
            rA = *(const float4*)(lf + 12 * 1 + q * 4);
            rB = *(const float4*)(lf + 12 * 2 + q * 4);
            rC = *(const float4*)(lf + 12 * 3 + q * 4);
        }
        if (q < 2) { pA = ps[1]; pB = ps[2]; pC = ps[3]; }
    }

    lds_barrier();
    bf16x8 bx = *(const bf16x8*)&row[1][v][8 * q];

    for (int t = 0; t < NT; ++t) {
        // wave0 first: x(t+1) pack + LDS write + issue next prefetch.
        // Independent of z/gates, so its latency hides under them.
        if (wid == 0) {
            if (q < 3) {
                float xv[4] = { rA.x, rA.y, rA.z, rA.w };
                #pragma unroll
                for (int i = 0; i < 4; ++i) {
                    float x = fmaf(xv[i], Ac[i], pA * Bc[i]);
                    xv[i] = (x == x) ? x : 1.0f;
                }
                unsigned pk0 = (unsigned)f2bf(xv[0]) | ((unsigned)f2bf(xv[1]) << 16);
                unsigned pk1 = (unsigned)f2bf(xv[2]) | ((unsigned)f2bf(xv[3]) << 16);
                *(uint2*)&row[t & 1][v][4 * q] = make_uint2(pk0, pk1);
            }
            rA = rB; rB = rC; pA = pB; pB = pC;
            int tn = (t + 4 < NT) ? (t + 4) : (NT - 1);
            if (q < 3) rC = *(const float4*)(lf + 12 * tn + q * 4);
            if (q < 2) pC = ps[tn];
        }

        // z = W^T * [x_t | h_{t-1}] + b  (wave0: 3 tiles, wave1: 2 tiles)
        f32x4 z[3];
        z[0] = __builtin_amdgcn_mfma_f32_16x16x32_bf16(aW[0], bx, cB[0], 0, 0, 0);
        z[1] = __builtin_amdgcn_mfma_f32_16x16x32_bf16(aW[1], bx, cB[1], 0, 0, 0);
        if (wid == 0)
            z[2] = __builtin_amdgcn_mfma_f32_16x16x32_bf16(aW[2], bx, cB[2], 0, 0, 0);

        // gates (reg 0..3 = i,f,g,o), lane-local cell update, publish h_t
        #pragma unroll
        for (int l = 0; l < 3; ++l) {
            if (l < 2 || wid == 0) {
                float si = fsig(z[l][0]);
                float sf = fsig(z[l][1]);
                float tg = ftanh(z[l][2]);
                float so = fsig(z[l][3]);
                float cn = fmaf(sf, cst[l], si * tg);
                cst[l] = cn;
                h32[l] = so * ftanh(cn);
                row[t & 1][v][12 + 4 * (TTB + l) + q] = f2bf(h32[l]);
            }
        }

        lds_barrier();
        // gather next B-frag: one aligned b128 per lane
        bf16x8 bxn = *(const bf16x8*)&row[t & 1][v][8 * q];

        // wave1: head d = relu(h_t @ W_d + b_d) via MFMA (A zeros x-cols),
        // lc partials + quad butterfly, one predicated 12B store per step.
        // Runs while wave0 starts the next step's MFMAs.
        if (wid == 1) {
            f32x4 d = __builtin_amdgcn_mfma_f32_16x16x32_bf16(aH, bxn, cD, 0, 0, 0);
            float dr[4];
            #pragma unroll
            for (int reg = 0; reg < 4; ++reg) dr[reg] = fmaxf(d[reg], 0.0f);
            float p[3];
            #pragma unroll
            for (int j = 0; j < 3; ++j) {
                float acc = pb0[j];
                #pragma unroll
                for (int reg = 0; reg < 4; ++reg) acc = fmaf(dr[reg], wlc[reg][j], acc);
                acc += __shfl_xor(acc, 16);
                acc += __shfl_xor(acc, 32);
                p[j] = acc;
            }
            if (q == (t & 3)) {
                float* o = lcout + (size_t)t * 3;
                *(float2*)o = make_float2(p[0], p[1]);
                o[2] = p[2];
            }
        }
        bx = bxn;
    }

    #pragma unroll
    for (int l = 0; l < 3; ++l) {
        if (l < 2 || wid == 0) {
            int u = 4 * (TTB + l) + q;
            out_h[(size_t)gv * 20 + u] = h32[l];
            out_c[(size_t)gv * 20 + u] = cst[l];
        }
    }
}

extern "C" void kernel_launch(void* const* d_in, const int* in_sizes, int n_in,
                              void* d_out, int out_size, void* d_ws, size_t ws_size,
                              hipStream_t stream) {
    const float* lead   = (const float*)d_in[0];
    const float* traj   = (const float*)d_in[1];
    const float* hidden = (const float*)d_in[2];
    const float* W_k    = (const float*)d_in[3];
    const float* W_r    = (const float*)d_in[4];
    const float* b_l    = (const float*)d_in[5];
    const float* W_d    = (const float*)d_in[6];
    const float* b_d    = (const float*)d_in[7];
    const float* W_lc   = (const float*)d_in[8];
    const float* b_lc   = (const float*)d_in[9];

    float* out    = (float*)d_out;
    float* out_tt = out;
    float* out_lc = out + (size_t)NVEH * NT;
    float* out_h  = out_lc + (size_t)NVEH * NT * 3;
    float* out_c  = out_h + (size_t)NVEH * 20;

    hipMemcpyAsync(out_tt, traj, (size_t)NVEH * NT * sizeof(float),
                   hipMemcpyDeviceToDevice, stream);

    lstm_scan_kernel<<<dim3(NVEH / 16), dim3(128), 0, stream>>>(
        lead, traj, hidden, W_k, W_r, b_l, W_d, b_d, W_lc, b_lc,
        out_lc, out_h, out_c);
}

// Round 2
// 657.620 us; speedup vs baseline: 1.2114x; 1.0979x over previous
//
#include <hip/hip_runtime.h>

#define NVEH 8192
#define NT   512

typedef short bf16x8 __attribute__((ext_vector_type(8)));
typedef float f32x4  __attribute__((ext_vector_type(4)));

__device__ __forceinline__ float fsig(float x) {
    float e = __builtin_amdgcn_exp2f(-1.44269504f * x);
    return __builtin_amdgcn_rcpf(1.0f + e);
}
__device__ __forceinline__ float ftanh(float x) {
    float e = __builtin_amdgcn_exp2f(-2.88539008f * x);
    return 2.0f * __builtin_amdgcn_rcpf(1.0f + e) - 1.0f;
}
__device__ __forceinline__ unsigned short f2bf(float f) {
    union { float f; unsigned u; } vv; vv.f = f;
    unsigned r = vv.u + 0x7fff + ((vv.u >> 16) & 1);
    return (unsigned short)(r >> 16);
}

// LDS-only barrier: order ds ops across waves WITHOUT draining vmcnt
// (plain __syncthreads() would wait vmcnt(0) and stall on in-flight prefetch).
__device__ __forceinline__ void lds_barrier() {
    asm volatile("s_waitcnt lgkmcnt(0)" ::: "memory");
    __builtin_amdgcn_s_barrier();
    asm volatile("" ::: "memory");
}

// 4 waves per 16-vehicle group.
//   w0: z-tiles 0,1 (units 0..7)   w1: z-tiles 2,3 (units 8..15)
//   w2: z-tile 4   (units 16..19)
//   w3: POST-barrier only: head MFMA + lc + store + x-pack(t+2) + prefetch.
// Pre-barrier critical path is exactly: ds_read -> MFMA -> gates -> publish.
// Unit map u(tt,q) = 8*(tt>>1) + 2q + (tt&1) (tt<4), 16+q (tt==4) makes each
// w0/w1 lane own ADJACENT units -> h publish is ONE packed ds_write_b32.
__global__ __launch_bounds__(256) void lstm_scan_kernel(
    const float* __restrict__ lead, const float* __restrict__ traj,
    const float* __restrict__ hidden,
    const float* __restrict__ W_k, const float* __restrict__ W_r,
    const float* __restrict__ b_l, const float* __restrict__ W_d,
    const float* __restrict__ b_d, const float* __restrict__ W_lc,
    const float* __restrict__ b_lc,
    float* __restrict__ out_lc, float* __restrict__ out_h, float* __restrict__ out_c)
{
    // row[buf][v]: 40 shorts (80 B): [0..11]=x, [12..31]=h, [32..39]=pad.
    __shared__ alignas(16) unsigned short row[2][16][40];

    const int tid  = threadIdx.x;
    const int wid  = tid >> 6;
    const int lane = tid & 63;
    const int q    = lane >> 4;
    const int v    = lane & 15;
    const int gv   = blockIdx.x * 16 + v;

    const int ntile = (wid < 2) ? 2 : (wid == 2) ? 1 : 0;

    // ---- z-MFMA fragments (w0..w2): A = W^T permuted, bias as C
    bf16x8 aW[2]; f32x4 cB[2];
    float h32[2], cst[2];
    int uu[2];
    #pragma unroll
    for (int l = 0; l < 2; ++l) {
        if (l < ntile) {
            const int tt = 2 * wid + l;
            #pragma unroll
            for (int j = 0; j < 8; ++j) {
                int k  = q * 8 + j;
                int qv = v >> 2, rv = v & 3;           // within-tile output row v -> (quad, gate)
                int u  = (tt < 4) ? (8 * (tt >> 1) + 2 * qv + (tt & 1)) : (16 + qv);
                int col = rv * 20 + u;                 // keras gate-major [i|f|c|o]
                float w = (k < 12) ? W_k[k * 80 + col] : W_r[(k - 12) * 80 + col];
                aW[l][j] = (short)f2bf(w);
            }
            uu[l] = (tt < 4) ? (8 * (tt >> 1) + 2 * q + (tt & 1)) : (16 + q);
            #pragma unroll
            for (int reg = 0; reg < 4; ++reg)
                cB[l][reg] = b_l[reg * 20 + uu[l]];
            h32[l] = hidden[(size_t)gv * 20 + uu[l]];
            cst[l] = hidden[(size_t)NVEH * 20 + (size_t)gv * 20 + uu[l]];
        }
    }

    // ---- initial h publish into row[0]
    if (wid < 2) {
        unsigned pk = (unsigned)f2bf(h32[0]) | ((unsigned)f2bf(h32[1]) << 16);
        *(unsigned*)&row[0][v][12 + 8 * wid + 2 * q] = pk;   // 4B-aligned (even idx)
    } else if (wid == 2) {
        row[0][v][28 + q] = f2bf(h32[0]);
    }

    // ---- w3-only: head MFMA consts, lc consts, x-coeffs, x(0)/x(1), prefetch
    const float* lf = lead + (size_t)gv * NT * 12;
    const float* ps = traj + (size_t)gv * NT;
    float* lcout    = out_lc + (size_t)gv * NT * 3;

    bf16x8 aH = {}; f32x4 cD = {};
    float wlc[4][3] = {}; float pb0[3] = {};
    float Ac[4], Bc[4];
    float4 rA = make_float4(0.f,0.f,0.f,0.f), rB = rA, rC = rA;
    float pA = 0.f, pB = 0.f, pC = 0.f;
    if (wid == 3) {
        #pragma unroll
        for (int j = 0; j < 8; ++j) {
            int k = q * 8 + j;
            aH[j] = (v < 10 && k >= 12) ? (short)f2bf(W_d[(k - 12) * 10 + v]) : (short)0;
        }
        #pragma unroll
        for (int reg = 0; reg < 4; ++reg) {
            int m = 4 * q + reg;
            cD[reg] = (m < 10) ? b_d[m] : 0.0f;
            #pragma unroll
            for (int j = 0; j < 3; ++j)
                wlc[reg][j] = (m < 10) ? W_lc[m * 3 + j] : 0.0f;
        }
        #pragma unroll
        for (int j = 0; j < 3; ++j) pb0[j] = (q == 0) ? b_lc[j] : 0.0f;

        #pragma unroll
        for (int i = 0; i < 4; ++i) {
            int e = 4 * q + i;
            if (e < 3)      { Ac[i] =  0.01f;  Bc[i] = -0.01f; }
            else if (e < 6) { Ac[i] = -0.01f;  Bc[i] =  0.01f; }
            else            { Ac[i] =  0.025f; Bc[i] =  0.0f;  }
        }

        // x(0) -> row[0], x(1) -> row[1]
        #pragma unroll
        for (int s = 0; s < 2; ++s) {
            float4 r0 = make_float4(0.f,0.f,0.f,0.f); float p0s = 0.f;
            if (q < 3) r0 = *(const float4*)(lf + 12 * s + q * 4);
            if (q < 2) p0s = ps[s];
            if (q < 3) {
                float xv[4] = { r0.x, r0.y, r0.z, r0.w };
                #pragma unroll
                for (int i = 0; i < 4; ++i) {
                    float x = fmaf(xv[i], Ac[i], p0s * Bc[i]);
                    xv[i] = (x == x) ? x : 1.0f;
                }
                unsigned pk0 = (unsigned)f2bf(xv[0]) | ((unsigned)f2bf(xv[1]) << 16);
                unsigned pk1 = (unsigned)f2bf(xv[2]) | ((unsigned)f2bf(xv[3]) << 16);
                *(uint2*)&row[s][v][4 * q] = make_uint2(pk0, pk1);
            }
        }
        // depth-3 prefetch of x(2), x(3), x(4)
        if (q < 3) {
            rA = *(const float4*)(lf + 12 * 2 + q * 4);
            rB = *(const float4*)(lf + 12 * 3 + q * 4);
            rC = *(const float4*)(lf + 12 * 4 + q * 4);
        }
        if (q < 2) { pA = ps[2]; pB = ps[3]; pC = ps[4]; }
    }

    lds_barrier();
    bf16x8 bx = *(const bf16x8*)&row[0][v][8 * q];

    for (int t = 0; t < NT; ++t) {
        const int nxt = (t + 1) & 1;

        // ---- pre-barrier: z-MFMA + gates + publish (w0..w2 only)
        if (wid < 3) {
            f32x4 z0 = __builtin_amdgcn_mfma_f32_16x16x32_bf16(aW[0], bx, cB[0], 0, 0, 0);
            f32x4 z1;
            if (ntile == 2)
                z1 = __builtin_amdgcn_mfma_f32_16x16x32_bf16(aW[1], bx, cB[1], 0, 0, 0);

            {   // unit uu[0]
                float si = fsig(z0[0]);
                float sf = fsig(z0[1]);
                float tg = ftanh(z0[2]);
                float so = fsig(z0[3]);
                float cn = fmaf(sf, cst[0], si * tg);
                cst[0] = cn;
                h32[0] = so * ftanh(cn);
            }
            if (ntile == 2) {  // unit uu[1]
                float si = fsig(z1[0]);
                float sf = fsig(z1[1]);
                float tg = ftanh(z1[2]);
                float so = fsig(z1[3]);
                float cn = fmaf(sf, cst[1], si * tg);
                cst[1] = cn;
                h32[1] = so * ftanh(cn);
            }

            if (wid < 2) {
                unsigned pk = (unsigned)f2bf(h32[0]) | ((unsigned)f2bf(h32[1]) << 16);
                *(unsigned*)&row[nxt][v][12 + 8 * wid + 2 * q] = pk;
            } else {
                row[nxt][v][28 + q] = f2bf(h32[0]);
            }
        }

        lds_barrier();
        // gather next B-frag (x_{t+1} | h_t): one aligned b128 per lane
        bf16x8 bxn = *(const bf16x8*)&row[nxt][v][8 * q];

        // ---- post-barrier: w3 does head + lc + store + x-pack(t+2) + prefetch,
        // overlapping w0..w2's next-step MFMA+gates.
        if (wid == 3) {
            f32x4 d = __builtin_amdgcn_mfma_f32_16x16x32_bf16(aH, bxn, cD, 0, 0, 0);
            float dr[4];
            #pragma unroll
            for (int reg = 0; reg < 4; ++reg) dr[reg] = fmaxf(d[reg], 0.0f);
            float p[3];
            #pragma unroll
            for (int j = 0; j < 3; ++j) {
                float acc = pb0[j];
                #pragma unroll
                for (int reg = 0; reg < 4; ++reg) acc = fmaf(dr[reg], wlc[reg][j], acc);
                acc += __shfl_xor(acc, 16);
                acc += __shfl_xor(acc, 32);
                p[j] = acc;
            }
            if (q == (t & 3)) {
                float* o = lcout + (size_t)t * 3;
                *(float2*)o = make_float2(p[0], p[1]);
                o[2] = p[2];
            }

            // x-pack for step t+2 into row[t&1] (its readers drained at the
            // barrier we just passed; next read is after the NEXT barrier).
            if (q < 3) {
                float xv[4] = { rA.x, rA.y, rA.z, rA.w };
                #pragma unroll
                for (int i = 0; i < 4; ++i) {
                    float x = fmaf(xv[i], Ac[i], pA * Bc[i]);
                    xv[i] = (x == x) ? x : 1.0f;
                }
                unsigned pk0 = (unsigned)f2bf(xv[0]) | ((unsigned)f2bf(xv[1]) << 16);
                unsigned pk1 = (unsigned)f2bf(xv[2]) | ((unsigned)f2bf(xv[3]) << 16);
                *(uint2*)&row[t & 1][v][4 * q] = make_uint2(pk0, pk1);
            }
            rA = rB; rB = rC; pA = pB; pB = pC;
            int tn = (t + 5 < NT) ? (t + 5) : (NT - 1);
            if (q < 3) rC = *(const float4*)(lf + 12 * tn + q * 4);
            if (q < 2) pC = ps[tn];
        }

        bx = bxn;
    }

    if (wid < 3) {
        #pragma unroll
        for (int l = 0; l < 2; ++l) {
            if (l < ntile) {
                out_h[(size_t)gv * 20 + uu[l]] = h32[l];
                out_c[(size_t)gv * 20 + uu[l]] = cst[l];
            }
        }
    }
}

extern "C" void kernel_launch(void* const* d_in, const int* in_sizes, int n_in,
                              void* d_out, int out_size, void* d_ws, size_t ws_size,
                              hipStream_t stream) {
    const float* lead   = (const float*)d_in[0];
    const float* traj   = (const float*)d_in[1];
    const float* hidden = (const float*)d_in[2];
    const float* W_k    = (const float*)d_in[3];
    const float* W_r    = (const float*)d_in[4];
    const float* b_l    = (const float*)d_in[5];
    const float* W_d    = (const float*)d_in[6];
    const float* b_d    = (const float*)d_in[7];
    const float* W_lc   = (const float*)d_in[8];
    const float* b_lc   = (const float*)d_in[9];

    float* out    = (float*)d_out;
    float* out_tt = out;
    float* out_lc = out + (size_t)NVEH * NT;
    float* out_h  = out_lc + (size_t)NVEH * NT * 3;
    float* out_c  = out_h + (size_t)NVEH * 20;

    hipMemcpyAsync(out_tt, traj, (size_t)NVEH * NT * sizeof(float),
                   hipMemcpyDeviceToDevice, stream);

    lstm_scan_kernel<<<dim3(NVEH / 16), dim3(256), 0, stream>>>(
        lead, traj, hidden, W_k, W_r, b_l, W_d, b_d, W_lc, b_lc,
        out_lc, out_h, out_c);
}